// Round 1
// baseline (533.782 us; speedup 1.0000x reference)
//
#include <hip/hip_runtime.h>

#define IN_F 128
#define OUT_F 128
#define NODES_PER_ITER 4

// ---------------------------------------------------------------------------
// Phase 1: scatter-add x[row[e]] into agg[col[e]], plus degree count.
// Thread = (edge, feature): 128 consecutive threads handle one edge's 128
// features -> coalesced 512B gather + coalesced atomic adds.
// ---------------------------------------------------------------------------
__global__ __launch_bounds__(256) void gcn_scatter(
    const float* __restrict__ x,
    const int* __restrict__ ei,       // [2*E]: row = ei[0..E), col = ei[E..2E)
    float* __restrict__ agg,          // [N, 128] zero-initialized
    float* __restrict__ deg,          // [N] zero-initialized
    int nEdges)
{
    const long long total = (long long)nEdges * IN_F;
    const long long stride = (long long)gridDim.x * blockDim.x;
    for (long long i = (long long)blockIdx.x * blockDim.x + threadIdx.x;
         i < total; i += stride) {
        const int e = (int)(i >> 7);        // edge id
        const int f = (int)(i & 127);       // feature id
        const int src = ei[e];
        const int dst = ei[nEdges + e];
        const float v = x[(long long)src * IN_F + f];
        atomicAdd(&agg[(long long)dst * IN_F + f], v);
        if (f == 0) atomicAdd(&deg[dst], 1.0f);
    }
}

// ---------------------------------------------------------------------------
// Phase 2: out = (agg / max(deg,1)) @ W.T + b
// W staged transposed+padded in LDS: Wt[k][o] = W[o][k]; inner read
// Wt[k][tid] is consecutive across lanes -> conflict-free. 4 nodes per
// iteration share each Wt read.
// ---------------------------------------------------------------------------
__global__ __launch_bounds__(128) void gcn_mm(
    const float* __restrict__ agg,
    const float* __restrict__ deg,
    const float* __restrict__ W,      // [128,128] row-major (out_f, in_f)
    const float* __restrict__ bias,   // [128]
    float* __restrict__ out,          // [N,128]
    int nNodes)
{
    __shared__ float Wt[IN_F][OUT_F + 1];          // padded: stride 129
    __shared__ float hrow[NODES_PER_ITER][IN_F];

    const int tid = threadIdx.x;  // 0..127 = output feature

    // Coalesced load of W, transposed store into LDS.
    // iter i: thread tid loads W[i][tid] (consecutive), writes Wt[tid][i]
    // (addr = tid*129 + i -> banks (tid + i) % 32, conflict-free).
    for (int i = 0; i < OUT_F; ++i) {
        Wt[tid][i] = W[i * IN_F + tid];
    }
    const float bv = bias[tid];
    __syncthreads();

    const long long start = (long long)blockIdx.x * NODES_PER_ITER;
    const long long step  = (long long)gridDim.x * NODES_PER_ITER;
    for (long long base = start; base < nNodes; base += step) {
        const int nv = (int)((nNodes - base) < NODES_PER_ITER ? (nNodes - base)
                                                              : NODES_PER_ITER);
        for (int j = 0; j < nv; ++j) {
            const long long n = base + j;
            float d = deg[n];
            d = d > 1.0f ? d : 1.0f;
            hrow[j][tid] = agg[n * IN_F + tid] / d;
        }
        __syncthreads();

        float acc[NODES_PER_ITER];
#pragma unroll
        for (int j = 0; j < NODES_PER_ITER; ++j) acc[j] = bv;

        for (int k = 0; k < IN_F; ++k) {
            const float w = Wt[k][tid];
#pragma unroll
            for (int j = 0; j < NODES_PER_ITER; ++j) {
                acc[j] += hrow[j][k] * w;   // hrow[j][k] is a broadcast read
            }
        }
        for (int j = 0; j < nv; ++j) {
            out[(base + j) * IN_F + tid] = acc[j];
        }
        __syncthreads();
    }
}

extern "C" void kernel_launch(void* const* d_in, const int* in_sizes, int n_in,
                              void* d_out, int out_size, void* d_ws, size_t ws_size,
                              hipStream_t stream)
{
    const float* x   = (const float*)d_in[0];
    const int*   ei  = (const int*)d_in[1];
    // d_in[2] = n_nodes scalar (unused; derived from sizes)
    const float* W   = (const float*)d_in[3];
    const float* b   = (const float*)d_in[4];
    float*       out = (float*)d_out;

    const int nNodes = in_sizes[0] / IN_F;   // 50000
    const int nEdges = in_sizes[1] / 2;      // 800000

    float* agg = (float*)d_ws;                                   // [N,128]
    float* deg = agg + (size_t)nNodes * IN_F;                    // [N]

    // Zero the accumulators (poison-proof, deterministic per call).
    hipMemsetAsync(d_ws, 0, ((size_t)nNodes * IN_F + nNodes) * sizeof(float),
                   stream);

    // Phase 1: scatter
    {
        const long long total = (long long)nEdges * IN_F;
        int blocks = (int)((total + 255) / 256);
        if (blocks > 16384) blocks = 16384;
        gcn_scatter<<<blocks, 256, 0, stream>>>(x, ei, agg, deg, nEdges);
    }

    // Phase 2: normalize + linear
    {
        const int blocks = (nNodes + NODES_PER_ITER - 1) / NODES_PER_ITER;
        gcn_mm<<<blocks, 128, 0, stream>>>(agg, deg, W, b, out, nNodes);
    }
}

// Round 2
// 438.884 us; speedup vs baseline: 1.2162x; 1.2162x over previous
//
#include <hip/hip_runtime.h>

#define IN_F 128
#define OUT_F 128
#define SCAN_T 1024

// ---------------------------------------------------------------------------
// 1) Histogram of destination nodes (int atomics over 200KB -> L2-resident).
// ---------------------------------------------------------------------------
__global__ __launch_bounds__(256) void k_hist(
    const int* __restrict__ ei, int* __restrict__ deg_i, int nEdges)
{
    int e = blockIdx.x * blockDim.x + threadIdx.x;
    if (e < nEdges) {
        atomicAdd(&deg_i[ei[nEdges + e]], 1);
    }
}

// ---------------------------------------------------------------------------
// 2) Exclusive scan of deg_i[n] -> off[n], plus a mutable copy in cursor[n].
//    Single block, 1024 threads, chunked + Hillis-Steele over partials.
// ---------------------------------------------------------------------------
__global__ __launch_bounds__(SCAN_T) void k_scan(
    const int* __restrict__ deg_i, int* __restrict__ off,
    int* __restrict__ cursor, int n)
{
    __shared__ int part[SCAN_T];
    const int t = threadIdx.x;
    const int chunk = (n + SCAN_T - 1) / SCAN_T;
    const int lo = t * chunk;
    const int hi = (lo + chunk < n) ? (lo + chunk) : n;

    int s = 0;
    for (int i = lo; i < hi; ++i) s += deg_i[i];
    part[t] = s;
    __syncthreads();

    for (int ofs = 1; ofs < SCAN_T; ofs <<= 1) {
        int v = (t >= ofs) ? part[t - ofs] : 0;
        __syncthreads();
        part[t] += v;
        __syncthreads();
    }

    int base = (t == 0) ? 0 : part[t - 1];
    for (int i = lo; i < hi; ++i) {
        off[i] = base;
        cursor[i] = base;
        base += deg_i[i];
    }
}

// ---------------------------------------------------------------------------
// 3) Bucket the edges: perm[pos] = src, grouped by dst.
// ---------------------------------------------------------------------------
__global__ __launch_bounds__(256) void k_scatter_ids(
    const int* __restrict__ ei, int* __restrict__ cursor,
    int* __restrict__ perm, int nEdges)
{
    int e = blockIdx.x * blockDim.x + threadIdx.x;
    if (e < nEdges) {
        const int src = ei[e];
        const int dst = ei[nEdges + e];
        const int pos = atomicAdd(&cursor[dst], 1);
        perm[pos] = src;
    }
}

// ---------------------------------------------------------------------------
// 4) Gather-side reduction: h[n][f] = (sum over edges of x[src][f]) / max(d,1)
//    No float atomics. 128 threads per node (2 nodes per 256-block).
//    x reads are coalesced 512B per edge; perm reads are wave-uniform.
// ---------------------------------------------------------------------------
__global__ __launch_bounds__(256) void k_gather(
    const float* __restrict__ x, const int* __restrict__ perm,
    const int* __restrict__ off, const int* __restrict__ deg_i,
    float* __restrict__ h, int nNodes)
{
    const int node = blockIdx.x * 2 + (threadIdx.x >> 7);
    const int tid = threadIdx.x & 127;
    if (node >= nNodes) return;

    const int s = off[node];
    const int d = deg_i[node];

    float acc = 0.0f;
    int i = 0;
    for (; i + 1 < d; i += 2) {
        const int s0 = perm[s + i];
        const int s1 = perm[s + i + 1];
        const float v0 = x[(long long)s0 * IN_F + tid];
        const float v1 = x[(long long)s1 * IN_F + tid];
        acc += v0;
        acc += v1;
    }
    if (i < d) {
        acc += x[(long long)perm[s + i] * IN_F + tid];
    }

    const float dn = d > 0 ? (float)d : 1.0f;
    h[(long long)node * IN_F + tid] = acc / dn;
}

// ---------------------------------------------------------------------------
// 5) out = h @ W.T + b, in place (h lives in d_out).
//    Thread o holds W row o in registers (32 x float4). h rows are read as
//    wave-uniform float4 broadcasts from global (L2-hot: gather just wrote
//    them). Barrier before overwriting the batch (h == out).
// ---------------------------------------------------------------------------
__global__ __launch_bounds__(128) void k_mm(
    const float* __restrict__ h, const float* __restrict__ W,
    const float* __restrict__ bias, float* __restrict__ out, int nNodes)
{
    const int o = threadIdx.x;

    float4 wr[32];
#pragma unroll
    for (int k = 0; k < 32; ++k) {
        wr[k] = reinterpret_cast<const float4*>(W)[o * 32 + k];
    }
    const float bv = bias[o];

    const long long step = (long long)gridDim.x * 4;
    for (long long base = (long long)blockIdx.x * 4; base < nNodes; base += step) {
        const int nv = (int)(((nNodes - base) < 4) ? (nNodes - base) : 4);

        float acc[4];
#pragma unroll
        for (int j = 0; j < 4; ++j) acc[j] = bv;

        for (int j = 0; j < nv; ++j) {
            const float4* hp = reinterpret_cast<const float4*>(h + (base + j) * IN_F);
#pragma unroll
            for (int k = 0; k < 32; ++k) {
                const float4 hv = hp[k];   // wave-uniform broadcast load
                acc[j] += hv.x * wr[k].x + hv.y * wr[k].y
                        + hv.z * wr[k].z + hv.w * wr[k].w;
            }
        }

        __syncthreads();   // all h reads of this batch done before overwrite
        for (int j = 0; j < nv; ++j) {
            out[(base + j) * IN_F + o] = acc[j];
        }
    }
}

extern "C" void kernel_launch(void* const* d_in, const int* in_sizes, int n_in,
                              void* d_out, int out_size, void* d_ws, size_t ws_size,
                              hipStream_t stream)
{
    const float* x   = (const float*)d_in[0];
    const int*   ei  = (const int*)d_in[1];
    const float* W   = (const float*)d_in[3];
    const float* b   = (const float*)d_in[4];
    float*       out = (float*)d_out;

    const int nNodes = in_sizes[0] / IN_F;   // 50000
    const int nEdges = in_sizes[1] / 2;      // 800000

    // Workspace layout (ints): deg_i[n], off[n], cursor[n], perm[E]  (~3.8MB)
    int* deg_i  = (int*)d_ws;
    int* off    = deg_i + nNodes;
    int* cursor = off + nNodes;
    int* perm   = cursor + nNodes;

    // Zero only the histogram (200KB).
    hipMemsetAsync(deg_i, 0, (size_t)nNodes * sizeof(int), stream);

    const int eb = (nEdges + 255) / 256;
    k_hist<<<eb, 256, 0, stream>>>(ei, deg_i, nEdges);
    k_scan<<<1, SCAN_T, 0, stream>>>(deg_i, off, cursor, nNodes);
    k_scatter_ids<<<eb, 256, 0, stream>>>(ei, cursor, perm, nEdges);

    // h is materialized in d_out, then transformed in place by k_mm.
    float* h = out;
    const int gb = (nNodes + 1) / 2;
    k_gather<<<gb, 256, 0, stream>>>(x, perm, off, deg_i, h, nNodes);

    k_mm<<<1024, 128, 0, stream>>>(h, W, b, out, nNodes);
}

// Round 3
// 423.223 us; speedup vs baseline: 1.2612x; 1.0370x over previous
//
#include <hip/hip_runtime.h>

#define IN_F 128
#define OUT_F 128
#define SCAN_T 1024

// ---------------------------------------------------------------------------
// 1) Histogram of destination nodes (int atomics over 200KB -> L2-resident).
// ---------------------------------------------------------------------------
__global__ __launch_bounds__(256) void k_hist(
    const int* __restrict__ ei, int* __restrict__ deg_i, int nEdges)
{
    int e = blockIdx.x * blockDim.x + threadIdx.x;
    if (e < nEdges) {
        atomicAdd(&deg_i[ei[nEdges + e]], 1);
    }
}

// ---------------------------------------------------------------------------
// 2) Exclusive scan of deg_i[n] -> off[n], plus a mutable copy in cursor[n].
// ---------------------------------------------------------------------------
__global__ __launch_bounds__(SCAN_T) void k_scan(
    const int* __restrict__ deg_i, int* __restrict__ off,
    int* __restrict__ cursor, int n)
{
    __shared__ int part[SCAN_T];
    const int t = threadIdx.x;
    const int chunk = (n + SCAN_T - 1) / SCAN_T;
    const int lo = t * chunk;
    const int hi = (lo + chunk < n) ? (lo + chunk) : n;

    int s = 0;
    for (int i = lo; i < hi; ++i) s += deg_i[i];
    part[t] = s;
    __syncthreads();

    for (int ofs = 1; ofs < SCAN_T; ofs <<= 1) {
        int v = (t >= ofs) ? part[t - ofs] : 0;
        __syncthreads();
        part[t] += v;
        __syncthreads();
    }

    int base = (t == 0) ? 0 : part[t - 1];
    for (int i = lo; i < hi; ++i) {
        off[i] = base;
        cursor[i] = base;
        base += deg_i[i];
    }
}

// ---------------------------------------------------------------------------
// 3) Bucket the edges: perm[pos] = src, grouped by dst.
// ---------------------------------------------------------------------------
__global__ __launch_bounds__(256) void k_scatter_ids(
    const int* __restrict__ ei, int* __restrict__ cursor,
    int* __restrict__ perm, int nEdges)
{
    int e = blockIdx.x * blockDim.x + threadIdx.x;
    if (e < nEdges) {
        const int src = ei[e];
        const int dst = ei[nEdges + e];
        const int pos = atomicAdd(&cursor[dst], 1);
        perm[pos] = src;
    }
}

// ---------------------------------------------------------------------------
// 4) Gather-side reduction: h[n] = (sum over in-edges of x[src]) / max(d,1)
//    64 lanes per node, float2 per lane (512B per wave-load = full row).
//    Degree loop unrolled x4 for ILP. No float atomics.
// ---------------------------------------------------------------------------
__global__ __launch_bounds__(256) void k_gather(
    const float* __restrict__ x, const int* __restrict__ perm,
    const int* __restrict__ off, const int* __restrict__ deg_i,
    float* __restrict__ h, int nNodes)
{
    const int node = blockIdx.x * 4 + (threadIdx.x >> 6);
    const int lane = threadIdx.x & 63;
    if (node >= nNodes) return;

    const int s = off[node];
    const int d = deg_i[node];
    const float2* __restrict__ x2 = reinterpret_cast<const float2*>(x);

    float ax = 0.0f, ay = 0.0f;
    int i = 0;
    for (; i + 4 <= d; i += 4) {
        const int s0 = perm[s + i + 0];
        const int s1 = perm[s + i + 1];
        const int s2 = perm[s + i + 2];
        const int s3 = perm[s + i + 3];
        const float2 v0 = x2[(long long)s0 * 64 + lane];
        const float2 v1 = x2[(long long)s1 * 64 + lane];
        const float2 v2 = x2[(long long)s2 * 64 + lane];
        const float2 v3 = x2[(long long)s3 * 64 + lane];
        ax += v0.x + v1.x + v2.x + v3.x;
        ay += v0.y + v1.y + v2.y + v3.y;
    }
    for (; i < d; ++i) {
        const float2 v = x2[(long long)perm[s + i] * 64 + lane];
        ax += v.x;
        ay += v.y;
    }

    const float inv = 1.0f / (float)(d > 0 ? d : 1);
    float2 r;
    r.x = ax * inv;
    r.y = ay * inv;
    reinterpret_cast<float2*>(h)[(long long)node * 64 + lane] = r;
}

// ---------------------------------------------------------------------------
// 5) out = h @ W.T + b, in place (h lives in d_out).
//    256 threads: o = tid&127 (output feature), g = tid>>7 selects 8 of the
//    block's 16 node rows. W row o in 32 float4 registers (fully unrolled,
//    compile-time indices only -> stays in VGPRs). h rows are broadcast
//    float4 loads from L2, 8 independent rows of ILP. One barrier before
//    the in-place overwrite.
// ---------------------------------------------------------------------------
#define MM_ROWS 8                       // rows per thread
#define MM_TILE (MM_ROWS * 2)           // nodes per block

__global__ __launch_bounds__(256) void k_mm(
    const float* __restrict__ h, const float* __restrict__ W,
    const float* __restrict__ bias, float* __restrict__ out, int nNodes)
{
    const int o = threadIdx.x & 127;
    const int g = threadIdx.x >> 7;
    const long long base = (long long)blockIdx.x * MM_TILE + (long long)g * MM_ROWS;

    const float4* __restrict__ W4 = reinterpret_cast<const float4*>(W);
    float4 wr[32];
#pragma unroll
    for (int k = 0; k < 32; ++k) wr[k] = W4[o * 32 + k];

    const float bv = bias[o];
    float acc[MM_ROWS];
#pragma unroll
    for (int r = 0; r < MM_ROWS; ++r) acc[r] = bv;

    const float4* __restrict__ hp[MM_ROWS];
#pragma unroll
    for (int r = 0; r < MM_ROWS; ++r)
        hp[r] = reinterpret_cast<const float4*>(h + (base + r) * IN_F);

#pragma unroll
    for (int k = 0; k < 32; ++k) {
        const float4 w = wr[k];
#pragma unroll
        for (int r = 0; r < MM_ROWS; ++r) {
            const float4 v = hp[r][k];      // wave-uniform broadcast load
            acc[r] += v.x * w.x + v.y * w.y + v.z * w.z + v.w * w.w;
        }
    }

    __syncthreads();   // all reads of this block's rows done before overwrite
#pragma unroll
    for (int r = 0; r < MM_ROWS; ++r) {
        out[(base + r) * IN_F + o] = acc[r];
    }
}

extern "C" void kernel_launch(void* const* d_in, const int* in_sizes, int n_in,
                              void* d_out, int out_size, void* d_ws, size_t ws_size,
                              hipStream_t stream)
{
    const float* x   = (const float*)d_in[0];
    const int*   ei  = (const int*)d_in[1];
    const float* W   = (const float*)d_in[3];
    const float* b   = (const float*)d_in[4];
    float*       out = (float*)d_out;

    const int nNodes = in_sizes[0] / IN_F;   // 50000
    const int nEdges = in_sizes[1] / 2;      // 800000

    // Workspace layout (ints): deg_i[n], off[n], cursor[n], perm[E]  (~3.8MB)
    int* deg_i  = (int*)d_ws;
    int* off    = deg_i + nNodes;
    int* cursor = off + nNodes;
    int* perm   = cursor + nNodes;

    hipMemsetAsync(deg_i, 0, (size_t)nNodes * sizeof(int), stream);

    const int eb = (nEdges + 255) / 256;
    k_hist<<<eb, 256, 0, stream>>>(ei, deg_i, nEdges);
    k_scan<<<1, SCAN_T, 0, stream>>>(deg_i, off, cursor, nNodes);
    k_scatter_ids<<<eb, 256, 0, stream>>>(ei, cursor, perm, nEdges);

    // h is materialized in d_out, then transformed in place by k_mm.
    float* h = out;
    const int gb = (nNodes + 3) / 4;
    k_gather<<<gb, 256, 0, stream>>>(x, perm, off, deg_i, h, nNodes);

    const int mb = (nNodes + MM_TILE - 1) / MM_TILE;   // 3125, exact
    k_mm<<<mb, 256, 0, stream>>>(h, W, b, out, nNodes);
}

// Round 5
// 265.277 us; speedup vs baseline: 2.0122x; 1.5954x over previous
//
#include <hip/hip_runtime.h>

#define IN_F 128
#define OUT_F 128
#define SCAN_T 1024

typedef unsigned int uint32;
typedef unsigned short ushort16;
using short8 = __attribute__((ext_vector_type(8))) short;   // 8 bf16 (4 VGPR)
using f32x4  = __attribute__((ext_vector_type(4))) float;   // MFMA acc

// f32 -> bf16 (round-to-nearest-even), as raw u16 in low bits.
__device__ __forceinline__ uint32 f2bf(float f) {
    const uint32 u = __float_as_uint(f);
    return (u + 0x7FFFu + ((u >> 16) & 1u)) >> 16;
}
// pack two f32 into bf16x2 dword: lo in bits[15:0], hi in bits[31:16]
__device__ __forceinline__ uint32 pack_bf2(float lo, float hi) {
    return f2bf(lo) | (f2bf(hi) << 16);
}

// ---------------------------------------------------------------------------
// 0) Convert x (nx4 float4s) and W (nw4 float4s) to bf16.
// ---------------------------------------------------------------------------
__global__ __launch_bounds__(256) void k_cvt(
    const float* __restrict__ x, const float* __restrict__ W,
    uint32* __restrict__ xb, uint32* __restrict__ wb, int nx4, int nw4)
{
    const int i4 = blockIdx.x * 256 + threadIdx.x;
    if (i4 < nx4) {
        const float4 v = reinterpret_cast<const float4*>(x)[i4];
        uint2 st;
        st.x = pack_bf2(v.x, v.y);
        st.y = pack_bf2(v.z, v.w);
        reinterpret_cast<uint2*>(xb)[i4] = st;
    } else if (i4 - nx4 < nw4) {
        const int j4 = i4 - nx4;
        const float4 v = reinterpret_cast<const float4*>(W)[j4];
        uint2 st;
        st.x = pack_bf2(v.x, v.y);
        st.y = pack_bf2(v.z, v.w);
        reinterpret_cast<uint2*>(wb)[j4] = st;
    }
}

// ---------------------------------------------------------------------------
// 1) Histogram of destination nodes (int atomics over 200KB -> L2-resident).
// ---------------------------------------------------------------------------
__global__ __launch_bounds__(256) void k_hist(
    const int* __restrict__ ei, int* __restrict__ deg_i, int nEdges)
{
    int e = blockIdx.x * blockDim.x + threadIdx.x;
    if (e < nEdges) {
        atomicAdd(&deg_i[ei[nEdges + e]], 1);
    }
}

// ---------------------------------------------------------------------------
// 2) Exclusive scan of deg_i -> off, plus a mutable copy in cursor.
// ---------------------------------------------------------------------------
__global__ __launch_bounds__(SCAN_T) void k_scan(
    const int* __restrict__ deg_i, int* __restrict__ off,
    int* __restrict__ cursor, int n)
{
    __shared__ int part[SCAN_T];
    const int t = threadIdx.x;
    const int chunk = (n + SCAN_T - 1) / SCAN_T;
    const int lo = t * chunk;
    const int hi = (lo + chunk < n) ? (lo + chunk) : n;

    int s = 0;
    for (int i = lo; i < hi; ++i) s += deg_i[i];
    part[t] = s;
    __syncthreads();

    for (int ofs = 1; ofs < SCAN_T; ofs <<= 1) {
        int v = (t >= ofs) ? part[t - ofs] : 0;
        __syncthreads();
        part[t] += v;
        __syncthreads();
    }

    int base = (t == 0) ? 0 : part[t - 1];
    for (int i = lo; i < hi; ++i) {
        off[i] = base;
        cursor[i] = base;
        base += deg_i[i];
    }
}

// ---------------------------------------------------------------------------
// 3) Bucket the edges: perm[pos] = src, grouped by dst.
// ---------------------------------------------------------------------------
__global__ __launch_bounds__(256) void k_scatter_ids(
    const int* __restrict__ ei, int* __restrict__ cursor,
    int* __restrict__ perm, int nEdges)
{
    int e = blockIdx.x * blockDim.x + threadIdx.x;
    if (e < nEdges) {
        const int src = ei[e];
        const int dst = ei[nEdges + e];
        const int pos = atomicAdd(&cursor[dst], 1);
        perm[pos] = src;
    }
}

// ---------------------------------------------------------------------------
// 4) Gather-side reduction over bf16 x: one wave per node, lane holds 2
//    features (bf16x2 dword). f32 accumulation, bf16 output row.
// ---------------------------------------------------------------------------
__global__ __launch_bounds__(256) void k_gather(
    const uint32* __restrict__ xb2,    // [N][64] bf16x2
    const int* __restrict__ perm,
    const int* __restrict__ off,
    const int* __restrict__ deg_i,
    uint32* __restrict__ hb2,          // [N][64] bf16x2
    int nNodes)
{
    const int node = (blockIdx.x << 2) + (threadIdx.x >> 6);
    const int lane = threadIdx.x & 63;
    if (node >= nNodes) return;

    const int s = off[node];
    const int d = deg_i[node];

    float ax = 0.0f, ay = 0.0f;
    int i = 0;
    for (; i + 4 <= d; i += 4) {
        const uint32 u0 = xb2[(size_t)perm[s + i + 0] * 64 + lane];
        const uint32 u1 = xb2[(size_t)perm[s + i + 1] * 64 + lane];
        const uint32 u2 = xb2[(size_t)perm[s + i + 2] * 64 + lane];
        const uint32 u3 = xb2[(size_t)perm[s + i + 3] * 64 + lane];
        ax += __uint_as_float(u0 << 16);
        ay += __uint_as_float(u0 & 0xFFFF0000u);
        ax += __uint_as_float(u1 << 16);
        ay += __uint_as_float(u1 & 0xFFFF0000u);
        ax += __uint_as_float(u2 << 16);
        ay += __uint_as_float(u2 & 0xFFFF0000u);
        ax += __uint_as_float(u3 << 16);
        ay += __uint_as_float(u3 & 0xFFFF0000u);
    }
    for (; i < d; ++i) {
        const uint32 u = xb2[(size_t)perm[s + i] * 64 + lane];
        ax += __uint_as_float(u << 16);
        ay += __uint_as_float(u & 0xFFFF0000u);
    }

    const float inv = 1.0f / (float)(d > 0 ? d : 1);
    hb2[(size_t)node * 64 + lane] = pack_bf2(ax * inv, ay * inv);
}

// ---------------------------------------------------------------------------
// 5) out = h @ W.T + b via mfma_f32_16x16x32_bf16.
//    Wave computes 32 rows x 128 cols: 2 m-tiles, 8 n-tiles, K=128 in 4 steps.
//    A-frag: h[m0+(lane&15)][kt*32+(lane>>4)*8 ..+8]   (16B load)
//    B-frag: B[k][n]=W[n][k] -> W[n0+(lane&15)][kt*32+(lane>>4)*8 ..+8]
//    C/D:    col=lane&15, row=(lane>>4)*4+reg  (m89-verified layout)
// ---------------------------------------------------------------------------
__global__ __launch_bounds__(256) void k_mm(
    const ushort16* __restrict__ hbf,   // [M][128] bf16
    const ushort16* __restrict__ wbf,   // [128][128] bf16 (row=out_f, col=in_f)
    const float* __restrict__ bias,
    float* __restrict__ out, int nNodes)
{
    const int wave = threadIdx.x >> 6;
    const int lane = threadIdx.x & 63;
    const int m0 = blockIdx.x * 128 + wave * 32;   // 32 rows per wave
    const int lrow = lane & 15;
    const int kgrp = lane >> 4;

    // A fragments for 2 m-tiles x 4 k-tiles
    short8 a[2][4];
#pragma unroll
    for (int mt = 0; mt < 2; ++mt) {
        int mrow = m0 + mt * 16 + lrow;
        if (mrow >= nNodes) mrow = nNodes - 1;          // clamp (tail safety)
        const ushort16* hrow = hbf + (size_t)mrow * IN_F;
#pragma unroll
        for (int kt = 0; kt < 4; ++kt) {
            a[mt][kt] = *reinterpret_cast<const short8*>(hrow + kt * 32 + kgrp * 8);
        }
    }

#pragma unroll
    for (int nt = 0; nt < 8; ++nt) {
        const int n0 = nt * 16;
        const ushort16* wrow = wbf + (size_t)(n0 + lrow) * IN_F;
        const float bv = bias[n0 + lrow];

        f32x4 acc0 = {bv, bv, bv, bv};
        f32x4 acc1 = {bv, bv, bv, bv};
#pragma unroll
        for (int kt = 0; kt < 4; ++kt) {
            const short8 b = *reinterpret_cast<const short8*>(wrow + kt * 32 + kgrp * 8);
            acc0 = __builtin_amdgcn_mfma_f32_16x16x32_bf16(a[0][kt], b, acc0, 0, 0, 0);
            acc1 = __builtin_amdgcn_mfma_f32_16x16x32_bf16(a[1][kt], b, acc1, 0, 0, 0);
        }
#pragma unroll
        for (int r = 0; r < 4; ++r) {
            const int row0 = m0 + kgrp * 4 + r;
            const int row1 = m0 + 16 + kgrp * 4 + r;
            if (row0 < nNodes) out[(size_t)row0 * OUT_F + n0 + lrow] = acc0[r];
            if (row1 < nNodes) out[(size_t)row1 * OUT_F + n0 + lrow] = acc1[r];
        }
    }
}

extern "C" void kernel_launch(void* const* d_in, const int* in_sizes, int n_in,
                              void* d_out, int out_size, void* d_ws, size_t ws_size,
                              hipStream_t stream)
{
    const float* x   = (const float*)d_in[0];
    const int*   ei  = (const int*)d_in[1];
    const float* W   = (const float*)d_in[3];
    const float* b   = (const float*)d_in[4];
    float*       out = (float*)d_out;

    const int nNodes = in_sizes[0] / IN_F;   // 50000
    const int nEdges = in_sizes[1] / 2;      // 800000

    // ws layout: deg_i[n] off[n] cursor[n] perm[E] hbf[n*128 bf16] wbf[16384 bf16]
    int* deg_i  = (int*)d_ws;
    int* off    = deg_i + nNodes;
    int* cursor = off + nNodes;
    int* perm   = cursor + nNodes;
    ushort16* hbf = (ushort16*)(perm + nEdges);
    ushort16* wbf = hbf + (size_t)nNodes * IN_F;

    // x_bf16 lives in d_out's first 12.8MB: dead before k_mm writes out.
    uint32* xb = (uint32*)d_out;

    (void)hipMemsetAsync(deg_i, 0, (size_t)nNodes * sizeof(int), stream);

    const int nx4 = (nNodes * IN_F) / 4;
    const int nw4 = (OUT_F * IN_F) / 4;
    k_cvt<<<(nx4 + nw4 + 255) / 256, 256, 0, stream>>>(x, W, xb, (uint32*)wbf,
                                                       nx4, nw4);

    const int eb = (nEdges + 255) / 256;
    k_hist<<<eb, 256, 0, stream>>>(ei, deg_i, nEdges);
    k_scan<<<1, SCAN_T, 0, stream>>>(deg_i, off, cursor, nNodes);
    k_scatter_ids<<<eb, 256, 0, stream>>>(ei, cursor, perm, nEdges);

    const int gb = (nNodes + 3) / 4;
    k_gather<<<gb, 256, 0, stream>>>(xb, perm, off, deg_i,
                                     (uint32*)hbf, nNodes);

    const int mb = (nNodes + 127) / 128;   // 391 blocks, tail clamped
    k_mm<<<mb, 256, 0, stream>>>(hbf, wbf, b, out, nNodes);
}

// Round 6
// 164.243 us; speedup vs baseline: 3.2500x; 1.6151x over previous
//
#include <hip/hip_runtime.h>

#define IN_F 128
#define OUT_F 128

typedef unsigned int uint32;
typedef unsigned short ushort16;
using short8 = __attribute__((ext_vector_type(8))) short;   // 8 bf16 (4 VGPR)
using f32x4  = __attribute__((ext_vector_type(4))) float;   // MFMA acc

// f32 -> bf16 (round-to-nearest-even), as raw u16 in low bits.
__device__ __forceinline__ uint32 f2bf(float f) {
    const uint32 u = __float_as_uint(f);
    return (u + 0x7FFFu + ((u >> 16) & 1u)) >> 16;
}
__device__ __forceinline__ uint32 pack_bf2(float lo, float hi) {
    return f2bf(lo) | (f2bf(hi) << 16);
}

// ---------------------------------------------------------------------------
// 0) Convert x (nx4 float4s) and W (nw4 float4s) to bf16.
// ---------------------------------------------------------------------------
__global__ __launch_bounds__(256) void k_cvt(
    const float* __restrict__ x, const float* __restrict__ W,
    uint32* __restrict__ xb, uint32* __restrict__ wb, int nx4, int nw4)
{
    const int i4 = blockIdx.x * 256 + threadIdx.x;
    if (i4 < nx4) {
        const float4 v = reinterpret_cast<const float4*>(x)[i4];
        uint2 st;
        st.x = pack_bf2(v.x, v.y);
        st.y = pack_bf2(v.z, v.w);
        reinterpret_cast<uint2*>(xb)[i4] = st;
    } else if (i4 - nx4 < nw4) {
        const int j4 = i4 - nx4;
        const float4 v = reinterpret_cast<const float4*>(W)[j4];
        uint2 st;
        st.x = pack_bf2(v.x, v.y);
        st.y = pack_bf2(v.z, v.w);
        reinterpret_cast<uint2*>(wb)[j4] = st;
    }
}

// ---------------------------------------------------------------------------
// 1) Histogram of destination nodes (int atomics over 200KB -> L2-resident).
// ---------------------------------------------------------------------------
__global__ __launch_bounds__(256) void k_hist(
    const int* __restrict__ ei, int* __restrict__ deg_i, int nEdges)
{
    int e = blockIdx.x * blockDim.x + threadIdx.x;
    if (e < nEdges) {
        atomicAdd(&deg_i[ei[nEdges + e]], 1);
    }
}

// ---------------------------------------------------------------------------
// 2) Three-phase parallel exclusive scan of deg_i[n]:
//    a) per-block (256-wide) exclusive scan -> escan, block sums -> bsum
//    b) single-block exclusive scan of bsum -> bbase
//    c) off[i] = cursor[i] = escan[i] + bbase[block]
// ---------------------------------------------------------------------------
__global__ __launch_bounds__(256) void k_scan_a(
    const int* __restrict__ deg_i, int* __restrict__ escan,
    int* __restrict__ bsum, int n)
{
    __shared__ int sh[256];
    const int t = threadIdx.x;
    const int i = blockIdx.x * 256 + t;
    int v = (i < n) ? deg_i[i] : 0;
    sh[t] = v;
    __syncthreads();
    // inclusive Hillis-Steele
    for (int ofs = 1; ofs < 256; ofs <<= 1) {
        int u = (t >= ofs) ? sh[t - ofs] : 0;
        __syncthreads();
        sh[t] += u;
        __syncthreads();
    }
    if (i < n) escan[i] = sh[t] - v;            // exclusive
    if (t == 255) bsum[blockIdx.x] = sh[255];
}

__global__ __launch_bounds__(256) void k_scan_b(
    const int* __restrict__ bsum, int* __restrict__ bbase, int nb)
{
    __shared__ int sh[256];
    const int t = threadIdx.x;
    int v = (t < nb) ? bsum[t] : 0;
    sh[t] = v;
    __syncthreads();
    for (int ofs = 1; ofs < 256; ofs <<= 1) {
        int u = (t >= ofs) ? sh[t - ofs] : 0;
        __syncthreads();
        sh[t] += u;
        __syncthreads();
    }
    if (t < nb) bbase[t] = sh[t] - v;           // exclusive
}

__global__ __launch_bounds__(256) void k_scan_c(
    const int* __restrict__ escan, const int* __restrict__ bbase,
    int* __restrict__ off, int* __restrict__ cursor, int n)
{
    const int i = blockIdx.x * 256 + threadIdx.x;
    if (i < n) {
        const int o = escan[i] + bbase[blockIdx.x];
        off[i] = o;
        cursor[i] = o;
    }
}

// ---------------------------------------------------------------------------
// 3) Bucket the edges: perm[pos] = src, grouped by dst.
// ---------------------------------------------------------------------------
__global__ __launch_bounds__(256) void k_scatter_ids(
    const int* __restrict__ ei, int* __restrict__ cursor,
    int* __restrict__ perm, int nEdges)
{
    int e = blockIdx.x * blockDim.x + threadIdx.x;
    if (e < nEdges) {
        const int src = ei[e];
        const int dst = ei[nEdges + e];
        const int pos = atomicAdd(&cursor[dst], 1);
        perm[pos] = src;
    }
}

// ---------------------------------------------------------------------------
// 4) Gather-side reduction over bf16 x: one wave per node, lane holds 2
//    features (bf16x2 dword). f32 accumulation, bf16 output row.
// ---------------------------------------------------------------------------
__global__ __launch_bounds__(256) void k_gather(
    const uint32* __restrict__ xb2,    // [N][64] bf16x2
    const int* __restrict__ perm,
    const int* __restrict__ off,
    const int* __restrict__ deg_i,
    uint32* __restrict__ hb2,          // [N][64] bf16x2
    int nNodes)
{
    const int node = (blockIdx.x << 2) + (threadIdx.x >> 6);
    const int lane = threadIdx.x & 63;
    if (node >= nNodes) return;

    const int s = off[node];
    const int d = deg_i[node];

    float ax = 0.0f, ay = 0.0f;
    int i = 0;
    for (; i + 4 <= d; i += 4) {
        const uint32 u0 = xb2[(size_t)perm[s + i + 0] * 64 + lane];
        const uint32 u1 = xb2[(size_t)perm[s + i + 1] * 64 + lane];
        const uint32 u2 = xb2[(size_t)perm[s + i + 2] * 64 + lane];
        const uint32 u3 = xb2[(size_t)perm[s + i + 3] * 64 + lane];
        ax += __uint_as_float(u0 << 16);
        ay += __uint_as_float(u0 & 0xFFFF0000u);
        ax += __uint_as_float(u1 << 16);
        ay += __uint_as_float(u1 & 0xFFFF0000u);
        ax += __uint_as_float(u2 << 16);
        ay += __uint_as_float(u2 & 0xFFFF0000u);
        ax += __uint_as_float(u3 << 16);
        ay += __uint_as_float(u3 & 0xFFFF0000u);
    }
    for (; i < d; ++i) {
        const uint32 u = xb2[(size_t)perm[s + i] * 64 + lane];
        ax += __uint_as_float(u << 16);
        ay += __uint_as_float(u & 0xFFFF0000u);
    }

    const float inv = 1.0f / (float)(d > 0 ? d : 1);
    hb2[(size_t)node * 64 + lane] = pack_bf2(ax * inv, ay * inv);
}

// ---------------------------------------------------------------------------
// 5) out = h @ W.T + b via mfma_f32_16x16x32_bf16.
//    Wave computes 32 rows x 128 cols: 2 m-tiles, 8 n-tiles, K=128 in 4 steps.
//    C/D: col=lane&15, row=(lane>>4)*4+reg  (m89-verified layout)
// ---------------------------------------------------------------------------
__global__ __launch_bounds__(256) void k_mm(
    const ushort16* __restrict__ hbf,   // [M][128] bf16
    const ushort16* __restrict__ wbf,   // [128][128] bf16 (row=out_f, col=in_f)
    const float* __restrict__ bias,
    float* __restrict__ out, int nNodes)
{
    const int wave = threadIdx.x >> 6;
    const int lane = threadIdx.x & 63;
    const int m0 = blockIdx.x * 128 + wave * 32;   // 32 rows per wave
    const int lrow = lane & 15;
    const int kgrp = lane >> 4;

    short8 a[2][4];
#pragma unroll
    for (int mt = 0; mt < 2; ++mt) {
        int mrow = m0 + mt * 16 + lrow;
        if (mrow >= nNodes) mrow = nNodes - 1;          // clamp (tail safety)
        const ushort16* hrow = hbf + (size_t)mrow * IN_F;
#pragma unroll
        for (int kt = 0; kt < 4; ++kt) {
            a[mt][kt] = *reinterpret_cast<const short8*>(hrow + kt * 32 + kgrp * 8);
        }
    }

#pragma unroll
    for (int nt = 0; nt < 8; ++nt) {
        const int n0 = nt * 16;
        const ushort16* wrow = wbf + (size_t)(n0 + lrow) * IN_F;
        const float bv = bias[n0 + lrow];

        f32x4 acc0 = {bv, bv, bv, bv};
        f32x4 acc1 = {bv, bv, bv, bv};
#pragma unroll
        for (int kt = 0; kt < 4; ++kt) {
            const short8 b = *reinterpret_cast<const short8*>(wrow + kt * 32 + kgrp * 8);
            acc0 = __builtin_amdgcn_mfma_f32_16x16x32_bf16(a[0][kt], b, acc0, 0, 0, 0);
            acc1 = __builtin_amdgcn_mfma_f32_16x16x32_bf16(a[1][kt], b, acc1, 0, 0, 0);
        }
#pragma unroll
        for (int r = 0; r < 4; ++r) {
            const int row0 = m0 + kgrp * 4 + r;
            const int row1 = m0 + 16 + kgrp * 4 + r;
            if (row0 < nNodes) out[(size_t)row0 * OUT_F + n0 + lrow] = acc0[r];
            if (row1 < nNodes) out[(size_t)row1 * OUT_F + n0 + lrow] = acc1[r];
        }
    }
}

extern "C" void kernel_launch(void* const* d_in, const int* in_sizes, int n_in,
                              void* d_out, int out_size, void* d_ws, size_t ws_size,
                              hipStream_t stream)
{
    const float* x   = (const float*)d_in[0];
    const int*   ei  = (const int*)d_in[1];
    const float* W   = (const float*)d_in[3];
    const float* b   = (const float*)d_in[4];
    float*       out = (float*)d_out;

    const int nNodes = in_sizes[0] / IN_F;   // 50000
    const int nEdges = in_sizes[1] / 2;      // 800000
    const int nb = (nNodes + 255) / 256;     // 196 scan blocks

    // ws layout (ints): deg_i[n] off[n] cursor[n] escan[n] bsum[nb] bbase[nb]
    //                   perm[E] | hbf[n*128 bf16] wbf[16384 bf16]
    int* deg_i  = (int*)d_ws;
    int* off    = deg_i + nNodes;
    int* cursor = off + nNodes;
    int* escan  = cursor + nNodes;
    int* bsum   = escan + nNodes;
    int* bbase  = bsum + nb;
    int* perm   = bbase + nb;
    ushort16* hbf = (ushort16*)(perm + nEdges);
    ushort16* wbf = hbf + (size_t)nNodes * IN_F;

    // x_bf16 lives in d_out's first 12.8MB: dead before k_mm writes out.
    uint32* xb = (uint32*)d_out;

    (void)hipMemsetAsync(deg_i, 0, (size_t)nNodes * sizeof(int), stream);

    const int nx4 = (nNodes * IN_F) / 4;
    const int nw4 = (OUT_F * IN_F) / 4;
    k_cvt<<<(nx4 + nw4 + 255) / 256, 256, 0, stream>>>(x, W, xb, (uint32*)wbf,
                                                       nx4, nw4);

    const int eb = (nEdges + 255) / 256;
    k_hist<<<eb, 256, 0, stream>>>(ei, deg_i, nEdges);

    k_scan_a<<<nb, 256, 0, stream>>>(deg_i, escan, bsum, nNodes);
    k_scan_b<<<1, 256, 0, stream>>>(bsum, bbase, nb);
    k_scan_c<<<nb, 256, 0, stream>>>(escan, bbase, off, cursor, nNodes);

    k_scatter_ids<<<eb, 256, 0, stream>>>(ei, cursor, perm, nEdges);

    const int gb = (nNodes + 3) / 4;
    k_gather<<<gb, 256, 0, stream>>>(xb, perm, off, deg_i,
                                     (uint32*)hbf, nNodes);

    const int mb = (nNodes + 127) / 128;   // 391 blocks, tail clamped
    k_mm<<<mb, 256, 0, stream>>>(hbf, wbf, b, out, nNodes);
}